// Round 4
// baseline (667.347 us; speedup 1.0000x reference)
//
#include <hip/hip_runtime.h>
#include <hip/hip_bf16.h>
#include <math.h>
#include <cstdio>

// TMSA block, fp32 I/O, bf16 MFMA internals, pre-packed bf16 weights.
// ws layout (bytes):
//   [0,          37748736)   xw    bf16 [98304][192]  (LN1 out; later LN2 out)
//   [37748736,  75497472)    xwm   bf16 [98304][192]  (xw + pos_bias)
//   [75497472,  150994944)   attn  bf16 [98304][384]  (attn out; later MLP hidden)
//   [150994944, 264241152)   qkv   bf16 [3][4608][128][32] (hd pad 30->32, q pre-scaled)
//   [264241152, 264634368)   biasrT bf16 [6][128 col][128 row] (transposed rpb gather)
//   [264634368, 265671168)   packed weights/biases (see offsets in launch)
// res (x + proj) lives in d_out (fp32), updated in-place by fc2.

typedef __hip_bfloat16 bf16;
typedef __attribute__((ext_vector_type(8))) short short8;
typedef __attribute__((ext_vector_type(4))) unsigned short us4;
typedef __attribute__((ext_vector_type(4))) float f32x4;

#define SCALE_F 0.18257418583505536f   // 30^-0.5
#define SZPE 18874368u                 // elems per qkv tensor: 4608*128*32

__device__ __forceinline__ bf16  f2b(float v){ return __float2bfloat16(v); }
__device__ __forceinline__ float bu2f(unsigned short u){
    union { unsigned int i; float f; } x; x.i = ((unsigned int)u) << 16; return x.f;
}
__device__ __forceinline__ f32x4 mfma16(short8 a, short8 b, f32x4 c){
    return __builtin_amdgcn_mfma_f32_16x16x32_bf16(a, b, c, 0, 0, 0);
}

// async global->LDS, 16B per lane; LDS dest is wave-uniform base + lane*16.
__device__ __forceinline__ void gld16(const bf16* g, bf16* s){
    __builtin_amdgcn_global_load_lds(
        (const __attribute__((address_space(1))) unsigned int*)g,
        (__attribute__((address_space(3))) unsigned int*)s, 16, 0, 0);
}

__device__ __forceinline__ void wait_vm0(){
    asm volatile("s_waitcnt vmcnt(0)" ::: "memory");
}

// fast gelu with exact-erf semantics: A&S 7.1.26, |err(erf)| <= 1.5e-7
// (invisible under bf16 output rounding). ~13 VALU + 1 trans vs ~35 for erff.
__device__ __forceinline__ float gelu_erf(float x){
    float z  = fabsf(x) * 0.70710678118654752f;
    float t  = __builtin_amdgcn_rcpf(fmaf(0.3275911f, z, 1.f));
    float p  = fmaf(fmaf(fmaf(fmaf(1.061405429f, t, -1.453152027f),
                              t, 1.421413741f), t, -0.284496736f), t, 0.254829592f) * t;
    float e  = __expf(-z * z);
    float er = fmaf(-p, e, 1.f);          // erf(z), z >= 0
    er = (x >= 0.f) ? er : -er;
    return 0.5f * x * (1.f + er);
}

// XCD-aware bijective block swizzle: consecutive work ids land on one XCD.
// All GEMM grids are multiples of 8.
__device__ __forceinline__ int xswz(){
    return (blockIdx.x & 7) * ((int)gridDim.x >> 3) + ((int)blockIdx.x >> 3);
}

// Swin region label for (window, token): mask[win][i][j] == 0 iff label_i == label_j.
__device__ __forceinline__ int wincnt(int win, int tok){
    int d = (win >> 8) * 2 + (tok >> 6);
    int h = ((win >> 4) & 15) * 8 + ((tok >> 3) & 7);
    int w = (win & 15) * 8 + (tok & 7);
    int rd = (d >= 4) + (d >= 5);
    int rh = (h >= 120) + (h >= 124);
    int rw = (w >= 120) + (w >= 124);
    return (rd * 3 + rh) * 3 + rw;
}

// ---------------------------------------------------------------- weight packing
__global__ __launch_bounds__(256) void k_pack_qkv(const float* __restrict__ w,
                                                  const float* __restrict__ bias,
                                                  bf16* __restrict__ Bt,
                                                  float* __restrict__ bb)
{
    int idx = blockIdx.x * 256 + threadIdx.x;      // < 110592
    int n = idx / 192, k = idx - n * 192;
    int three = n / 192;
    int rem = n - three * 192, nh = rem >> 5, hdp = rem & 31;
    int srcc = three * 180 + nh * 30 + hdp;
    float v = 0.f;
    if (hdp < 30 && k < 180) v = w[(size_t)k * 540 + srcc];
    if (three == 0) v *= SCALE_F;
    Bt[(size_t)n * 192 + k] = f2b(v);
    if (k == 0) bb[n] = (hdp < 30) ? ((three == 0 ? SCALE_F : 1.f) * bias[srcc]) : 0.f;
}

// generic: Bt[n][k] (NP x KP) = w[k][n] (K x NW), zero-padded.
__global__ __launch_bounds__(256) void k_pack(const float* __restrict__ w,
                                              int NW, int K, int KP,
                                              bf16* __restrict__ Bt)
{
    int idx = blockIdx.x * 256 + threadIdx.x;
    int n = idx / KP, k = idx - n * KP;
    float v = (n < NW && k < K) ? w[(size_t)k * NW + n] : 0.f;
    Bt[idx] = f2b(v);
}

// ---------------------------------------------------------------- rpb gather (transposed, bf16)
__global__ __launch_bounds__(256) void k_rpbg(const float* __restrict__ rpb,
                                              const int* __restrict__ rpi,
                                              bf16* __restrict__ biasrT)
{
    int n = blockIdx.x * 256 + threadIdx.x;       // < 98304
    int nh = n >> 14, rc = n & 16383;
    int row = rc >> 7, col = rc & 127;
    biasrT[((size_t)nh * 128 + col) * 128 + row] = f2b(rpb[rpi[rc] * 6 + nh]);
}

// zero attn pad cols 360..383 (stride-384 buffer)
__global__ __launch_bounds__(256) void k_zpad(bf16* __restrict__ attn)
{
    int gi = blockIdx.x * 256 + threadIdx.x;      // < 294912
    int row = gi / 3, part = gi - row * 3;
    *(uint4*)&attn[(size_t)row * 384 + 360 + part * 8] = make_uint4(0u,0u,0u,0u);
}

// ---------------------------------------------------------------- LayerNorm
template<bool ROLL_PB>
__global__ __launch_bounds__(256) void k_ln(const float* __restrict__ x,
                                            const float* __restrict__ g,
                                            const float* __restrict__ b,
                                            const float* __restrict__ pb,
                                            bf16* __restrict__ xw,
                                            bf16* __restrict__ xwm)
{
    int row  = blockIdx.x * 4 + (threadIdx.x >> 6);
    int lane = threadIdx.x & 63;
    const float* src;
    if (ROLL_PB) {
        int win = row >> 7, tok = row & 127;
        int wd = win >> 8, wh = (win >> 4) & 15, ww = win & 15;
        int td = tok >> 6, th = (tok >> 3) & 7, tw = tok & 7;
        int d = wd * 2 + td + 1; if (d >= 6) d -= 6;
        int h = (wh * 8 + th + 4) & 127;
        int w = (ww * 8 + tw + 4) & 127;
        src = x + ((size_t)((d * 128 + h) * 128 + w)) * 180;
    } else {
        src = x + (size_t)row * 180;
    }
    float v0 = src[lane];
    float v1 = src[lane + 64];
    float v2 = (lane < 52) ? src[lane + 128] : 0.f;
    float s  = v0 + v1 + v2;
    float ss = v0*v0 + v1*v1 + v2*v2;
    #pragma unroll
    for (int o = 32; o > 0; o >>= 1) { s += __shfl_xor(s, o, 64); ss += __shfl_xor(ss, o, 64); }
    float mean = s * (1.f/180.f);
    float var  = ss * (1.f/180.f) - mean*mean;
    float rstd = rsqrtf(var + 1e-5f);

    bf16* dst = xw + (size_t)row * 192;
    float y0 = (v0-mean)*rstd*g[lane]     + b[lane];
    float y1 = (v1-mean)*rstd*g[lane+64]  + b[lane+64];
    float y2 = (lane < 52) ? ((v2-mean)*rstd*g[lane+128] + b[lane+128]) : 0.f;
    dst[lane]      = f2b(y0);
    dst[lane+64]   = f2b(y1);
    if (lane < 52) dst[lane+128] = f2b(y2);
    if (lane < 12) dst[180+lane] = f2b(0.f);
    if (ROLL_PB) {
        const float* pbr = pb + (size_t)(row & 63) * 180;
        bf16* dm = xwm + (size_t)row * 192;
        dm[lane]      = f2b(y0 + pbr[lane]);
        dm[lane+64]   = f2b(y1 + pbr[lane+64]);
        if (lane < 52) dm[lane+128] = f2b(y2 + pbr[lane+128]);
        if (lane < 12) dm[180+lane] = f2b(0.f);
    }
}

// ---------------------------------------------------------------- MFMA GEMM core v4
// C[128 x 64] tile of A[M x KP](bf16) @ Bt[N][KP](bf16, pre-transposed).
// Double-buffered prefetch: issue next K-step's global_load_lds BEFORE computing
// the current one; single raw s_barrier + vmcnt(0) per K-step AFTER compute
// (loads fly under the MFMAs). sched_barrier(0) pins boundaries (rule #18).
// LDS linear, content chunk-swizzled via pre-swizzled global source;
// ds_read applies the same XOR. Bank-even for all fragment reads.
template<int KP, bool DUAL>
__device__ __forceinline__ void mm2(const bf16* __restrict__ A,
                                    const bf16* __restrict__ Bt1,
                                    const bf16* __restrict__ Bt2,
                                    bf16* As, bf16* Bs1, bf16* Bs2,
                                    int m0, int n0,
                                    f32x4 (&acc1)[2][4], f32x4 (&acc2)[2][4])
{
    constexpr int NS = KP / 64;
    const int tid = threadIdx.x;
    const int w = tid >> 6, l = tid & 63, q = l >> 4, c = l & 15;
    const int lr = l >> 3, lj = l & 7;
    const int swz = ((lj ^ lr) << 3);             // pre-swizzled source chunk (elems)

    auto stage = [&](int ks, int buf){
        bf16* as = As + buf * (128 * 64);
        #pragma unroll
        for (int e = 0; e < 4; e++) {             // A: 128 rows, 8 rows per wave-load
            int m = (e * 4 + w) * 8 + lr;
            gld16(&A[(size_t)(m0 + m) * KP + ks * 64 + swz], &as[((e * 4 + w) * 8) * 64]);
        }
        bf16* b1 = Bs1 + buf * (64 * 64);
        #pragma unroll
        for (int e = 0; e < 2; e++) {             // B: 64 rows
            int n = (e * 4 + w) * 8 + lr;
            gld16(&Bt1[(size_t)(n0 + n) * KP + ks * 64 + swz], &b1[((e * 4 + w) * 8) * 64]);
            if (DUAL) {
                bf16* b2 = Bs2 + buf * (64 * 64);
                gld16(&Bt2[(size_t)(n0 + n) * KP + ks * 64 + swz], &b2[((e * 4 + w) * 8) * 64]);
            }
        }
    };

    stage(0, 0);
    wait_vm0();
    __builtin_amdgcn_sched_barrier(0);
    __builtin_amdgcn_s_barrier();
    __builtin_amdgcn_sched_barrier(0);

    #pragma unroll
    for (int ks = 0; ks < NS; ks++) {
        const int cur = ks & 1;
        if (ks + 1 < NS) stage(ks + 1, cur ^ 1);  // prefetch: flies under the MFMAs
        const bf16* as  = As  + cur * (128 * 64);
        const bf16* b1s = Bs1 + cur * (64 * 64);
        const bf16* b2s = DUAL ? (Bs2 + cur * (64 * 64)) : nullptr;
        #pragma unroll
        for (int k32 = 0; k32 < 2; k32++) {
            int koff = (((k32 * 4 + q) ^ (c & 7)) << 3);
            short8 a[2];
            #pragma unroll
            for (int mt = 0; mt < 2; mt++)
                a[mt] = *(const short8*)&as[(w * 32 + mt * 16 + c) * 64 + koff];
            #pragma unroll
            for (int nt = 0; nt < 4; nt++) {
                short8 b1 = *(const short8*)&b1s[(nt * 16 + c) * 64 + koff];
                #pragma unroll
                for (int mt = 0; mt < 2; mt++) acc1[mt][nt] = mfma16(a[mt], b1, acc1[mt][nt]);
                if (DUAL) {
                    short8 b2 = *(const short8*)&b2s[(nt * 16 + c) * 64 + koff];
                    #pragma unroll
                    for (int mt = 0; mt < 2; mt++) acc2[mt][nt] = mfma16(a[mt], b2, acc2[mt][nt]);
                }
            }
        }
        __builtin_amdgcn_sched_barrier(0);
        wait_vm0();                               // next-step loads landed (under compute)
        __builtin_amdgcn_s_barrier();             // all waves done reading cur
        __builtin_amdgcn_sched_barrier(0);
    }
}

// epilogue LDS roundtrip swizzle: chunk ^= (row>>2)&7 (writer and reader agree).
__device__ __forceinline__ int cs_idx(int row, int colt){
    return row * 64 + ((((colt >> 3) ^ ((row >> 2) & 7)) << 3) | (colt & 7));
}

// qkv GEMM: KP=192, N=576 packed; vectorized scatter to qkv via LDS roundtrip.
__global__ __launch_bounds__(256) void k_qkv(const bf16* __restrict__ A,
                                             const bf16* __restrict__ Bt,
                                             const float* __restrict__ bb,
                                             bf16* __restrict__ outq)
{
    __shared__ __align__(16) bf16 As[2 * 128 * 64];
    __shared__ __align__(16) bf16 Bs[2 * 64 * 64];
    int bid = xswz();                             // 6912 = 768 * 9, n-fastest
    int n0 = (bid % 9) * 64, m0 = (bid / 9) * 128;
    f32x4 a1[2][4] = {}, a2[2][4];
    mm2<192, false>(A, Bt, nullptr, As, Bs, nullptr, m0, n0, a1, a2);

    int tid = threadIdx.x, w = tid >> 6, l = tid & 63, q = l >> 4, c = l & 15;
    bf16* Cs = As;
    #pragma unroll
    for (int mt = 0; mt < 2; mt++)
      #pragma unroll
      for (int nt = 0; nt < 4; nt++)
        #pragma unroll
        for (int r = 0; r < 4; r++) {
            int row = w * 32 + mt * 16 + q * 4 + r;
            int colt = nt * 16 + c;
            Cs[cs_idx(row, colt)] = f2b(a1[mt][nt][r] + bb[n0 + colt]);
        }
    __syncthreads();
    int win = m0 >> 7;
    #pragma unroll
    for (int e = 0; e < 4; e++) {
        int gi = e * 256 + tid;                   // < 1024
        int row = gi >> 3, j = gi & 7, c8 = j * 8;
        int col = n0 + c8;
        int three = col / 192, rem = col - three * 192;
        int nh = rem >> 5, hdp = rem & 31;
        bf16* dst = outq + (size_t)three * SZPE + ((size_t)(win * 6 + nh) * 128 + row) * 32 + hdp;
        *(uint4*)dst = *(const uint4*)&Cs[row * 64 + ((j ^ ((row >> 2) & 7)) << 3)];
    }
}

// proj GEMM: KP=384 (attn stride), N pad 192; window-reverse + roll + residual -> d_out.
__global__ __launch_bounds__(256) void k_proj(const bf16* __restrict__ A,
                                              const bf16* __restrict__ Bt,
                                              const float* __restrict__ bias,
                                              const float* __restrict__ xin,
                                              float* __restrict__ res)
{
    __shared__ __align__(16) bf16 As[2 * 128 * 64];
    __shared__ __align__(16) bf16 Bs[2 * 64 * 64];
    int bid = xswz();                             // 2304 = 768 * 3
    int n0 = (bid % 3) * 64, m0 = (bid / 3) * 128;
    f32x4 a1[2][4] = {}, a2[2][4];
    mm2<384, false>(A, Bt, nullptr, As, Bs, nullptr, m0, n0, a1, a2);

    int w = threadIdx.x >> 6, l = threadIdx.x & 63, q = l >> 4, c = l & 15;
    #pragma unroll
    for (int mt = 0; mt < 2; mt++)
      #pragma unroll
      for (int r = 0; r < 4; r++) {
        int row = m0 + w * 32 + mt * 16 + q * 4 + r;
        int win = row >> 7, tok = row & 127;
        int wd = win >> 8, wh = (win >> 4) & 15, ww = win & 15;
        int td = tok >> 6, th = (tok >> 3) & 7, tw = tok & 7;
        int d = wd * 2 + td + 1; if (d >= 6) d -= 6;
        int h = (wh * 8 + th + 4) & 127;
        int wcol = (ww * 8 + tw + 4) & 127;
        size_t base = ((size_t)((d * 128 + h) * 128 + wcol)) * 180;
        #pragma unroll
        for (int nt = 0; nt < 4; nt++) {
            int col = n0 + nt * 16 + c;
            if (col < 180)
                res[base + col] = xin[base + col] + a1[mt][nt][r] + bias[col];
        }
      }
}

// fc1: KP=192, N pad 384 dual; gelu(x1)*x2 -> hid [98304][384] via LDS roundtrip.
__global__ __launch_bounds__(256) void k_fc1(const bf16* __restrict__ A,
                                             const bf16* __restrict__ Bt1,
                                             const float* __restrict__ bb1,
                                             const bf16* __restrict__ Bt2,
                                             const float* __restrict__ bb2,
                                             bf16* __restrict__ hid)
{
    __shared__ __align__(16) bf16 As[2 * 128 * 64];
    __shared__ __align__(16) bf16 Bs1[2 * 64 * 64];
    __shared__ __align__(16) bf16 Bs2[2 * 64 * 64];
    int bid = xswz();                             // 4608 = 768 * 6
    int n0 = (bid % 6) * 64, m0 = (bid / 6) * 128;
    f32x4 a1[2][4] = {}, a2[2][4] = {};
    mm2<192, true>(A, Bt1, Bt2, As, Bs1, Bs2, m0, n0, a1, a2);

    int tid = threadIdx.x, w = tid >> 6, l = tid & 63, q = l >> 4, c = l & 15;
    bf16* Cs = As;
    #pragma unroll
    for (int mt = 0; mt < 2; mt++)
      #pragma unroll
      for (int nt = 0; nt < 4; nt++)
        #pragma unroll
        for (int r = 0; r < 4; r++) {
            int row = w * 32 + mt * 16 + q * 4 + r;
            int colt = nt * 16 + c;
            int col = n0 + colt;
            float hv = 0.f;
            if (col < 360)
                hv = gelu_erf(a1[mt][nt][r] + bb1[col]) * (a2[mt][nt][r] + bb2[col]);
            Cs[cs_idx(row, colt)] = f2b(hv);
        }
    __syncthreads();
    #pragma unroll
    for (int e = 0; e < 4; e++) {
        int gi = e * 256 + tid;
        int row = gi >> 3, j = gi & 7, c8 = j * 8;
        *(uint4*)&hid[(size_t)(m0 + row) * 384 + n0 + c8] =
            *(const uint4*)&Cs[row * 64 + ((j ^ ((row >> 2) & 7)) << 3)];
    }
}

// fc2: KP=384 (hid stride), N pad 192; out += hid@w2 + b (in-place fp32)
__global__ __launch_bounds__(256) void k_fc2(const bf16* __restrict__ A,
                                             const bf16* __restrict__ Bt,
                                             const float* __restrict__ bias,
                                             float* __restrict__ out)
{
    __shared__ __align__(16) bf16 As[2 * 128 * 64];
    __shared__ __align__(16) bf16 Bs[2 * 64 * 64];
    int bid = xswz();                             // 2304
    int n0 = (bid % 3) * 64, m0 = (bid / 3) * 128;
    f32x4 a1[2][4] = {}, a2[2][4];
    mm2<384, false>(A, Bt, nullptr, As, Bs, nullptr, m0, n0, a1, a2);

    int w = threadIdx.x >> 6, l = threadIdx.x & 63, q = l >> 4, c = l & 15;
    #pragma unroll
    for (int mt = 0; mt < 2; mt++)
      #pragma unroll
      for (int nt = 0; nt < 4; nt++)
        #pragma unroll
        for (int r = 0; r < 4; r++) {
            int row = m0 + w * 32 + mt * 16 + q * 4 + r;
            int col = n0 + nt * 16 + c;
            if (col < 180) {
                size_t idx = (size_t)row * 180 + col;
                out[idx] = out[idx] + a1[mt][nt][r] + bias[col];
            }
        }
}

// ---------------------------------------------------------------- MFMA attention v2
// Q/K fragments loaded direct from global; mask analytic; bias from transposed
// bf16 table; Vts/Ps XOR-swizzled; LDS 43520B -> 3 blocks/CU.
template<bool MUT>
__global__ __launch_bounds__(256) void k_attn(const bf16* __restrict__ qkv,
                                              const bf16* __restrict__ biasrT,
                                              bf16* __restrict__ aout)
{
    __shared__ __align__(16) bf16 Vts[32 * 136];
    __shared__ __align__(16) bf16 Ps[128 * 136];

    int wh = blockIdx.x, win = wh / 6, nh = wh - win * 6;
    const bf16* qg = qkv + (size_t)wh * 4096;
    const bf16* kg = qg + (size_t)SZPE;
    const bf16* vg = qg + 2 * (size_t)SZPE;
    int tid = threadIdx.x, w = tid >> 6, l = tid & 63, q = l >> 4, c = l & 15;

    // stage V transposed (swizzled): 2 x uint4 global loads per thread
    #pragma unroll
    for (int e = 0; e < 2; e++) {
        int base = (e * 256 + tid) * 8;          // < 4096
        int tok = base >> 5, hd0 = base & 31;
        uint4 vv = *(const uint4*)&vg[base];
        const bf16* pv = (const bf16*)&vv;
        #pragma unroll
        for (int i = 0; i < 8; i++) {
            int hd = hd0 + i;
            Vts[hd * 136 + (tok ^ (((hd >> 3) & 3) << 3))] = pv[i];
        }
    }

    // QK^T direct from global (A/B fragments are contiguous 16B in [128][32] layout)
    f32x4 S[2][8];
    #pragma unroll
    for (int mt = 0; mt < 2; mt++)
        #pragma unroll
        for (int nt = 0; nt < 8; nt++) S[mt][nt] = (f32x4){0.f, 0.f, 0.f, 0.f};
    {
        short8 a[2];
        #pragma unroll
        for (int mt = 0; mt < 2; mt++) {
            int rq = w * 32 + mt * 16 + c;
            if (MUT) rq ^= 64;                   // swap halves for mutual attn
            a[mt] = *(const short8*)&qg[rq * 32 + q * 8];
        }
        #pragma unroll
        for (int nt = 0; nt < 8; nt++) {
            short8 b = *(const short8*)&kg[(nt * 16 + c) * 32 + q * 8];
            #pragma unroll
            for (int mt = 0; mt < 2; mt++) S[mt][nt] = mfma16(a[mt], b, S[mt][nt]);
        }
    }

    // region labels for analytic mask
    int rcnt[2][4], ccnt[8];
    #pragma unroll
    for (int mt = 0; mt < 2; mt++)
        #pragma unroll
        for (int r = 0; r < 4; r++) {
            int row = w * 32 + mt * 16 + q * 4 + r;
            rcnt[mt][r] = wincnt(win, MUT ? (row & 63) : row);
        }
    #pragma unroll
    for (int nt = 0; nt < 8; nt++) {
        int col = nt * 16 + c;
        ccnt[nt] = wincnt(win, MUT ? (col & 63) : col);
    }

    float mx[2][4];
    #pragma unroll
    for (int mt = 0; mt < 2; mt++)
      #pragma unroll
      for (int r = 0; r < 4; r++) mx[mt][r] = -3.0e38f;

    #pragma unroll
    for (int mt = 0; mt < 2; mt++)
      #pragma unroll
      for (int nt = 0; nt < 8; nt++) {
        float bv[4];
        if (!MUT) {
            int col = nt * 16 + c;
            us4 bb = *(const us4*)&biasrT[((size_t)(nh * 128 + col)) * 128
                                          + w * 32 + mt * 16 + q * 4];
            #pragma unroll
            for (int r = 0; r < 4; r++) bv[r] = bu2f(bb[r]);
        }
        bool valid = (w < 2) == (nt < 4);        // wave-uniform (MUT only)
        #pragma unroll
        for (int r = 0; r < 4; r++) {
            float s = S[mt][nt][r];
            if (MUT) {
                s = (rcnt[mt][r] == ccnt[nt]) ? s : s - 100.f;
                s = valid ? s : -30000.f;
            } else {
                s += bv[r];
                if (rcnt[mt][r] != ccnt[nt]) s -= 100.f;
            }
            S[mt][nt][r] = s;
            mx[mt][r] = fmaxf(mx[mt][r], s);
        }
      }
    #pragma unroll
    for (int mt = 0; mt < 2; mt++)
      #pragma unroll
      for (int r = 0; r < 4; r++) {
          float m = mx[mt][r];
          #pragma unroll
          for (int o = 1; o < 16; o <<= 1) m = fmaxf(m, __shfl_xor(m, o, 64));
          mx[mt][r] = m;
      }

    float sm[2][4] = {};
    #pragma unroll
    for (int mt = 0; mt < 2; mt++)
      #pragma unroll
      for (int nt = 0; nt < 8; nt++)
        #pragma unroll
        for (int r = 0; r < 4; r++) {
            float p = __expf(S[mt][nt][r] - mx[mt][r]);
            sm[mt][r] += p;
            Ps[(w * 32 + mt * 16 + q * 4 + r) * 136 + ((nt * 16 + c) ^ (q << 3))] = f2b(p);
        }
    #pragma unroll
    for (int mt = 0; mt < 2; mt++)
      #pragma unroll
      for (int r = 0; r < 4; r++) {
          float s = sm[mt][r];
          #pragma unroll
          for (int o = 1; o < 16; o <<= 1) s += __shfl_xor(s, o, 64);
          sm[mt][r] = s;
      }
    __syncthreads();                              // Vts + Ps ready

    f32x4 O[2][2];
    #pragma unroll
    for (int mt = 0; mt < 2; mt++)
        #pragma unroll
        for (int nt = 0; nt < 2; nt++) O[mt][nt] = (f32x4){0.f, 0.f, 0.f, 0.f};
    #pragma unroll
    for (int ks = 0; ks < 4; ks++) {
        short8 a[2];
        #pragma unroll
        for (int mt = 0; mt < 2; mt++) {
            int row = w * 32 + mt * 16 + c;
            int xr = ((c >> 2) & 3) << 3;         // = (row>>2)&3, matches writer q
            a[mt] = *(const short8*)&Ps[row * 136 + (ks * 32 + ((q << 3) ^ xr))];
        }
        #pragma unroll
        for (int nt = 0; nt < 2; nt++) {
            int hd = nt * 16 + c;
            int xv = ((hd >> 3) & 3) << 3;
            short8 b = *(const short8*)&Vts[hd * 136 + (ks * 32 + ((q << 3) ^ xv))];
            #pragma unroll
            for (int mt = 0; mt < 2; mt++) O[mt][nt] = mfma16(a[mt], b, O[mt][nt]);
        }
    }

    #pragma unroll
    for (int mt = 0; mt < 2; mt++)
      #pragma unroll
      for (int r = 0; r < 4; r++) {
          int row = w * 32 + mt * 16 + q * 4 + r;
          float inv = 1.f / sm[mt][r];
          #pragma unroll
          for (int nt = 0; nt < 2; nt++) {
              int col = nt * 16 + c;
              if (col < 30)
                  aout[((size_t)win * 128 + row) * 384 + (MUT ? 0 : 180) + nh * 30 + col] =
                      f2b(O[mt][nt][r] * inv);
          }
      }
}

// ---------------------------------------------------------------- launch
extern "C" void kernel_launch(void* const* d_in, const int* in_sizes, int n_in,
                              void* d_out, int out_size, void* d_ws, size_t ws_size,
                              hipStream_t stream)
{
    const float* x     = (const float*)d_in[0];
    const float* mask  = (const float*)d_in[1];
    const float* g1    = (const float*)d_in[2];
    const float* b1    = (const float*)d_in[3];
    const float* g2    = (const float*)d_in[4];
    const float* b2    = (const float*)d_in[5];
    const float* wqs   = (const float*)d_in[6];
    const float* bqs   = (const float*)d_in[7];
    const float* wqm   = (const float*)d_in[8];
    const float* bqm   = (const float*)d_in[9];
    const float* rpb   = (const float*)d_in[10];
    const float* posb  = (const float*)d_in[11];
    const float* wproj = (const float*)d_in[12];
    const float* bproj = (const float*)d_in[13];
    const float* w11   = (const float*)d_in[14];
    const float* bf11  = (const float*)d_in[15];
    const float* w12   = (const float*)d_in[16];
    const float* bf12  = (const float*)d_in[17];
    const float* w2    = (const float*)d_in[18];
    const float* bf2   = (const float*)d_in[19];
    const int*   rpi   = (const int*)d_in[20];
    float* out = (float*)d_out;
    (void)mask;   // mask is computed analytically in k_attn

    const size_t need = 265671168;
    if (ws_size < need) { fprintf(stderr, "[tmsa] ws too small: %zu < %zu\n", ws_size, need); return; }

    char* W = (char*)d_ws;
    bf16*  xw     = (bf16*)W;                              // [98304][192]
    bf16*  xwm    = (bf16*)(W + 37748736);                 // [98304][192]
    bf16*  attn   = (bf16*)(W + 75497472);                 // [98304][384]
    bf16*  qkv    = (bf16*)(W + 150994944);                // [3][4608][128][32]
    bf16*  biasrT = (bf16*)(W + 264241152);                // [6][128][128] bf16 (transposed)
    bf16*  Btqs   = (bf16*)(W + 264634368);                // [576][192]
    bf16*  Btqm   = (bf16*)(W + 264855552);                // [576][192]
    float* bbqs   = (float*)(W + 265076736);               // [576]
    float* bbqm   = (float*)(W + 265079040);               // [576]
    bf16*  Btproj = (bf16*)(W + 265081344);                // [192][384]
    bf16*  Btf11  = (bf16*)(W + 265228800);                // [384][192]
    bf16*  Btf12  = (bf16*)(W + 265376256);                // [384][192]
    bf16*  Btf2   = (bf16*)(W + 265523712);                // [192][384]

    k_rpbg<<<dim3(384), 256, 0, stream>>>(rpb, rpi, biasrT);
    k_pack_qkv<<<dim3(432), 256, 0, stream>>>(wqs, bqs, Btqs, bbqs);
    k_pack_qkv<<<dim3(432), 256, 0, stream>>>(wqm, bqm, Btqm, bbqm);
    k_pack<<<dim3(288), 256, 0, stream>>>(wproj, 180, 360, 384, Btproj);
    k_pack<<<dim3(288), 256, 0, stream>>>(w11,   360, 180, 192, Btf11);
    k_pack<<<dim3(288), 256, 0, stream>>>(w12,   360, 180, 192, Btf12);
    k_pack<<<dim3(288), 256, 0, stream>>>(w2,    180, 360, 384, Btf2);

    k_ln<true><<<dim3(24576), 256, 0, stream>>>(x, g1, b1, posb, xw, xwm);
    k_zpad<<<dim3(1152), 256, 0, stream>>>(attn);
    k_qkv<<<dim3(6912), 256, 0, stream>>>(xw, Btqs, bbqs, qkv);
    k_attn<false><<<dim3(4608), 256, 0, stream>>>(qkv, biasrT, attn);
    k_qkv<<<dim3(6912), 256, 0, stream>>>(xwm, Btqm, bbqm, qkv);
    k_attn<true><<<dim3(4608), 256, 0, stream>>>(qkv, biasrT, attn);
    k_proj<<<dim3(2304), 256, 0, stream>>>(attn, Btproj, bproj, x, out);
    k_ln<false><<<dim3(24576), 256, 0, stream>>>(out, g2, b2, nullptr, xw, nullptr);
    k_fc1<<<dim3(4608), 256, 0, stream>>>(xw, Btf11, bf11, Btf12, bf12, attn);
    k_fc2<<<dim3(2304), 256, 0, stream>>>(attn, Btf2, bf2, out);
}

// Round 5
// 590.899 us; speedup vs baseline: 1.1294x; 1.1294x over previous
//
#include <hip/hip_runtime.h>
#include <hip/hip_bf16.h>
#include <math.h>
#include <cstdio>

// TMSA block, fp32 I/O, bf16 MFMA internals, pre-packed bf16 weights.
// ws layout (bytes):
//   [0,          37748736)   xw    bf16 [98304][192]  (LN1 out; later LN2 out)
//   [37748736,  75497472)    xwm   bf16 [98304][192]  (xw + pos_bias)
//   [75497472,  150994944)   attn  bf16 [98304][384]  (attn out; later MLP hidden)
//   [150994944, 264241152)   qkv   bf16 [3][4608][128][32] (hd pad 30->32, q pre-scaled)
//   [264241152, 264634368)   biasrT bf16 [6][128 col][128 row] (transposed rpb gather)
//   [264634368, 265671168)   packed weights/biases (see offsets in launch)
// res (x + proj) lives in d_out (fp32), updated in-place by fc2.

typedef __hip_bfloat16 bf16;
typedef __attribute__((ext_vector_type(8))) short short8;
typedef __attribute__((ext_vector_type(4))) unsigned short us4;
typedef __attribute__((ext_vector_type(4))) float f32x4;

#define SCALE_F 0.18257418583505536f   // 30^-0.5
#define SZPE 18874368u                 // elems per qkv tensor: 4608*128*32

__device__ __forceinline__ bf16  f2b(float v){ return __float2bfloat16(v); }
__device__ __forceinline__ float bu2f(unsigned short u){
    union { unsigned int i; float f; } x; x.i = ((unsigned int)u) << 16; return x.f;
}
__device__ __forceinline__ f32x4 mfma16(short8 a, short8 b, f32x4 c){
    return __builtin_amdgcn_mfma_f32_16x16x32_bf16(a, b, c, 0, 0, 0);
}

// async global->LDS, 16B per lane; LDS dest is wave-uniform base + lane*16.
__device__ __forceinline__ void gld16(const bf16* g, bf16* s){
    __builtin_amdgcn_global_load_lds(
        (const __attribute__((address_space(1))) unsigned int*)g,
        (__attribute__((address_space(3))) unsigned int*)s, 16, 0, 0);
}

// fast gelu with exact-erf semantics: A&S 7.1.26, |err(erf)| <= 1.5e-7
// (invisible under bf16 output rounding). ~13 VALU + 1 trans vs ~35 for erff.
__device__ __forceinline__ float gelu_erf(float x){
    float z  = fabsf(x) * 0.70710678118654752f;
    float t  = __builtin_amdgcn_rcpf(fmaf(0.3275911f, z, 1.f));
    float p  = fmaf(fmaf(fmaf(fmaf(1.061405429f, t, -1.453152027f),
                              t, 1.421413741f), t, -0.284496736f), t, 0.254829592f) * t;
    float e  = __expf(-z * z);
    float er = fmaf(-p, e, 1.f);          // erf(z), z >= 0
    er = (x >= 0.f) ? er : -er;
    return 0.5f * x * (1.f + er);
}

// XCD-aware bijective block swizzle: consecutive work ids land on one XCD.
// All GEMM grids are multiples of 8.
__device__ __forceinline__ int xswz(){
    return (blockIdx.x & 7) * ((int)gridDim.x >> 3) + ((int)blockIdx.x >> 3);
}

// Swin region label for (window, token): mask[win][i][j] == 0 iff label_i == label_j.
__device__ __forceinline__ int wincnt(int win, int tok){
    int d = (win >> 8) * 2 + (tok >> 6);
    int h = ((win >> 4) & 15) * 8 + ((tok >> 3) & 7);
    int w = (win & 15) * 8 + (tok & 7);
    int rd = (d >= 4) + (d >= 5);
    int rh = (h >= 120) + (h >= 124);
    int rw = (w >= 120) + (w >= 124);
    return (rd * 3 + rh) * 3 + rw;
}

// window-reverse + roll: token row -> fp32 base offset (elements) in [D][H][W][C]
__device__ __forceinline__ size_t wrev_base(int row){
    int win = row >> 7, tok = row & 127;
    int wd = win >> 8, wh = (win >> 4) & 15, ww = win & 15;
    int td = tok >> 6, th = (tok >> 3) & 7, tw = tok & 7;
    int d = wd * 2 + td + 1; if (d >= 6) d -= 6;
    int h = (wh * 8 + th + 4) & 127;
    int wcol = (ww * 8 + tw + 4) & 127;
    return ((size_t)((d * 128 + h) * 128 + wcol)) * 180;
}

// ---------------------------------------------------------------- weight packing
__global__ __launch_bounds__(256) void k_pack_qkv(const float* __restrict__ w,
                                                  const float* __restrict__ bias,
                                                  bf16* __restrict__ Bt,
                                                  float* __restrict__ bb)
{
    int idx = blockIdx.x * 256 + threadIdx.x;      // < 110592
    int n = idx / 192, k = idx - n * 192;
    int three = n / 192;
    int rem = n - three * 192, nh = rem >> 5, hdp = rem & 31;
    int srcc = three * 180 + nh * 30 + hdp;
    float v = 0.f;
    if (hdp < 30 && k < 180) v = w[(size_t)k * 540 + srcc];
    if (three == 0) v *= SCALE_F;
    Bt[(size_t)n * 192 + k] = f2b(v);
    if (k == 0) bb[n] = (hdp < 30) ? ((three == 0 ? SCALE_F : 1.f) * bias[srcc]) : 0.f;
}

// generic: Bt[n][k] (NP x KP) = w[k][n] (K x NW), zero-padded.
__global__ __launch_bounds__(256) void k_pack(const float* __restrict__ w,
                                              int NW, int K, int KP,
                                              bf16* __restrict__ Bt)
{
    int idx = blockIdx.x * 256 + threadIdx.x;
    int n = idx / KP, k = idx - n * KP;
    float v = (n < NW && k < K) ? w[(size_t)k * NW + n] : 0.f;
    Bt[idx] = f2b(v);
}

// ---------------------------------------------------------------- rpb gather (transposed, bf16)
__global__ __launch_bounds__(256) void k_rpbg(const float* __restrict__ rpb,
                                              const int* __restrict__ rpi,
                                              bf16* __restrict__ biasrT)
{
    int n = blockIdx.x * 256 + threadIdx.x;       // < 98304
    int nh = n >> 14, rc = n & 16383;
    int row = rc >> 7, col = rc & 127;
    biasrT[((size_t)nh * 128 + col) * 128 + row] = f2b(rpb[rpi[rc] * 6 + nh]);
}

// zero attn pad cols 360..383 (stride-384 buffer)
__global__ __launch_bounds__(256) void k_zpad(bf16* __restrict__ attn)
{
    int gi = blockIdx.x * 256 + threadIdx.x;      // < 294912
    int row = gi / 3, part = gi - row * 3;
    *(uint4*)&attn[(size_t)row * 384 + 360 + part * 8] = make_uint4(0u,0u,0u,0u);
}

// ---------------------------------------------------------------- LayerNorm
template<bool ROLL_PB>
__global__ __launch_bounds__(256) void k_ln(const float* __restrict__ x,
                                            const float* __restrict__ g,
                                            const float* __restrict__ b,
                                            const float* __restrict__ pb,
                                            bf16* __restrict__ xw,
                                            bf16* __restrict__ xwm)
{
    int row  = blockIdx.x * 4 + (threadIdx.x >> 6);
    int lane = threadIdx.x & 63;
    const float* src;
    if (ROLL_PB) {
        src = x + wrev_base(row) - 0;  // note: roll for LN1 uses forward shift
        // forward roll (-SS): same formula as wrev but with +1/+4 shifts
        // (wrev_base implements exactly the (d+1, h+4, w+4) mapping used here)
    } else {
        src = x + (size_t)row * 180;
    }
    float v0 = src[lane];
    float v1 = src[lane + 64];
    float v2 = (lane < 52) ? src[lane + 128] : 0.f;
    float s  = v0 + v1 + v2;
    float ss = v0*v0 + v1*v1 + v2*v2;
    #pragma unroll
    for (int o = 32; o > 0; o >>= 1) { s += __shfl_xor(s, o, 64); ss += __shfl_xor(ss, o, 64); }
    float mean = s * (1.f/180.f);
    float var  = ss * (1.f/180.f) - mean*mean;
    float rstd = rsqrtf(var + 1e-5f);

    bf16* dst = xw + (size_t)row * 192;
    float y0 = (v0-mean)*rstd*g[lane]     + b[lane];
    float y1 = (v1-mean)*rstd*g[lane+64]  + b[lane+64];
    float y2 = (lane < 52) ? ((v2-mean)*rstd*g[lane+128] + b[lane+128]) : 0.f;
    dst[lane]      = f2b(y0);
    dst[lane+64]   = f2b(y1);
    if (lane < 52) dst[lane+128] = f2b(y2);
    if (lane < 12) dst[180+lane] = f2b(0.f);
    if (ROLL_PB) {
        const float* pbr = pb + (size_t)(row & 63) * 180;
        bf16* dm = xwm + (size_t)row * 192;
        dm[lane]      = f2b(y0 + pbr[lane]);
        dm[lane+64]   = f2b(y1 + pbr[lane+64]);
        if (lane < 52) dm[lane+128] = f2b(y2 + pbr[lane+128]);
        if (lane < 12) dm[180+lane] = f2b(0.f);
    }
}

// ---------------------------------------------------------------- MFMA GEMM core v3
// C[128 x 64] tile of A[M x KP](bf16) @ Bt[N][KP](bf16, pre-transposed).
// Staging via global_load_lds width=16: LDS linear [rows][64], content
// chunk-swizzled (LDS[r][j] = G[r][j^(r&7)]) via pre-swizzled global source;
// ds_read applies the same XOR. Bank-even for all fragment reads.
template<int KP, bool DUAL>
__device__ __forceinline__ void mm2(const bf16* __restrict__ A,
                                    const bf16* __restrict__ Bt1,
                                    const bf16* __restrict__ Bt2,
                                    bf16* As, bf16* Bs1, bf16* Bs2,
                                    int m0, int n0,
                                    f32x4 (&acc1)[2][4], f32x4 (&acc2)[2][4])
{
    const int tid = threadIdx.x;
    const int w = tid >> 6, l = tid & 63, q = l >> 4, c = l & 15;
    const int lr = l >> 3, lj = l & 7;
    const int swz = ((lj ^ lr) << 3);             // pre-swizzled source chunk (elems)
    #pragma unroll
    for (int ks = 0; ks < KP / 64; ks++) {
        #pragma unroll
        for (int e = 0; e < 4; e++) {             // A: 128 rows, 8 rows per wave-load
            int m = (e * 4 + w) * 8 + lr;
            gld16(&A[(size_t)(m0 + m) * KP + ks * 64 + swz], &As[((e * 4 + w) * 8) * 64]);
        }
        #pragma unroll
        for (int e = 0; e < 2; e++) {             // B: 64 rows
            int n = (e * 4 + w) * 8 + lr;
            gld16(&Bt1[(size_t)(n0 + n) * KP + ks * 64 + swz], &Bs1[((e * 4 + w) * 8) * 64]);
            if (DUAL)
                gld16(&Bt2[(size_t)(n0 + n) * KP + ks * 64 + swz], &Bs2[((e * 4 + w) * 8) * 64]);
        }
        __syncthreads();                          // drains vmcnt (gld writes landed)
        #pragma unroll
        for (int k32 = 0; k32 < 2; k32++) {
            int koff = (((k32 * 4 + q) ^ (c & 7)) << 3);
            short8 a[2];
            #pragma unroll
            for (int mt = 0; mt < 2; mt++)
                a[mt] = *(const short8*)&As[(w * 32 + mt * 16 + c) * 64 + koff];
            #pragma unroll
            for (int nt = 0; nt < 4; nt++) {
                short8 b1 = *(const short8*)&Bs1[(nt * 16 + c) * 64 + koff];
                #pragma unroll
                for (int mt = 0; mt < 2; mt++) acc1[mt][nt] = mfma16(a[mt], b1, acc1[mt][nt]);
                if (DUAL) {
                    short8 b2 = *(const short8*)&Bs2[(nt * 16 + c) * 64 + koff];
                    #pragma unroll
                    for (int mt = 0; mt < 2; mt++) acc2[mt][nt] = mfma16(a[mt], b2, acc2[mt][nt]);
                }
            }
        }
        __syncthreads();
    }
}

// epilogue LDS roundtrip swizzle (bf16 path): chunk ^= (row>>2)&7.
__device__ __forceinline__ int cs_idx(int row, int colt){
    return row * 64 + ((((colt >> 3) ^ ((row >> 2) & 7)) << 3) | (colt & 7));
}

// qkv GEMM: KP=192, N=576 packed; vectorized scatter to qkv via LDS roundtrip.
__global__ __launch_bounds__(256) void k_qkv(const bf16* __restrict__ A,
                                             const bf16* __restrict__ Bt,
                                             const float* __restrict__ bb,
                                             bf16* __restrict__ outq)
{
    __shared__ __align__(16) bf16 As[128 * 64];
    __shared__ __align__(16) bf16 Bs[64 * 64];
    int bid = xswz();                             // 6912 = 768 * 9, n-fastest
    int n0 = (bid % 9) * 64, m0 = (bid / 9) * 128;
    f32x4 a1[2][4] = {}, a2[2][4];
    mm2<192, false>(A, Bt, nullptr, As, Bs, nullptr, m0, n0, a1, a2);

    int tid = threadIdx.x, w = tid >> 6, l = tid & 63, q = l >> 4, c = l & 15;
    bf16* Cs = As;
    #pragma unroll
    for (int mt = 0; mt < 2; mt++)
      #pragma unroll
      for (int nt = 0; nt < 4; nt++)
        #pragma unroll
        for (int r = 0; r < 4; r++) {
            int row = w * 32 + mt * 16 + q * 4 + r;
            int colt = nt * 16 + c;
            Cs[cs_idx(row, colt)] = f2b(a1[mt][nt][r] + bb[n0 + colt]);
        }
    __syncthreads();
    int win = m0 >> 7;
    #pragma unroll
    for (int e = 0; e < 4; e++) {
        int gi = e * 256 + tid;                   // < 1024
        int row = gi >> 3, j = gi & 7, c8 = j * 8;
        int col = n0 + c8;
        int three = col / 192, rem = col - three * 192;
        int nh = rem >> 5, hdp = rem & 31;
        bf16* dst = outq + (size_t)three * SZPE + ((size_t)(win * 6 + nh) * 128 + row) * 32 + hdp;
        *(uint4*)dst = *(const uint4*)&Cs[row * 64 + ((j ^ ((row >> 2) & 7)) << 3)];
    }
}

// proj GEMM: KP=384 (attn stride), N pad 192; window-reverse + roll + residual -> d_out.
// Epilogue: fp32 LDS roundtrip in two 64-row half-passes ([64][76] pad), then
// float4-coalesced xin read + res write (16 lanes cover 256B/row).
__global__ __launch_bounds__(256) void k_proj(const bf16* __restrict__ A,
                                              const bf16* __restrict__ Bt,
                                              const float* __restrict__ bias,
                                              const float* __restrict__ xin,
                                              float* __restrict__ res)
{
    __shared__ __align__(16) char smem[24576];
    bf16*  As = (bf16*)smem;                      // 16384 B
    bf16*  Bs = (bf16*)(smem + 16384);            // 8192 B
    float* Cs = (float*)smem;                     // [64][76] = 19456 B per half
    int bid = xswz();                             // 2304 = 768 * 3
    int n0 = (bid % 3) * 64, m0 = (bid / 3) * 128;
    f32x4 a1[2][4] = {}, a2[2][4];
    mm2<384, false>(A, Bt, nullptr, As, Bs, nullptr, m0, n0, a1, a2);

    int tid = threadIdx.x, w = tid >> 6, l = tid & 63, q = l >> 4, c = l & 15;
    #pragma unroll
    for (int h = 0; h < 2; h++) {
        __syncthreads();                          // prev readers of Cs/As done
        if ((w >> 1) == h) {                      // waves 2h,2h+1 own rows h*64..+63
            #pragma unroll
            for (int mt = 0; mt < 2; mt++)
              #pragma unroll
              for (int nt = 0; nt < 4; nt++)
                #pragma unroll
                for (int r = 0; r < 4; r++) {
                    int rl = (w & 1) * 32 + mt * 16 + q * 4 + r;   // 0..63
                    Cs[rl * 76 + nt * 16 + c] = a1[mt][nt][r];
                }
        }
        __syncthreads();
        #pragma unroll
        for (int e = 0; e < 4; e++) {
            int slot = e * 256 + tid;             // < 1024: 64 rows x 16 quads
            int rl = slot >> 4, cq = slot & 15;
            int col = n0 + cq * 4;
            if (col < 180) {
                size_t base = wrev_base(m0 + h * 64 + rl) + col;
                float4 xi = *(const float4*)&xin[base];
                float4 bi = *(const float4*)&bias[col];
                const float* cp = &Cs[rl * 76 + cq * 4];
                float4 o;
                o.x = xi.x + cp[0] + bi.x;
                o.y = xi.y + cp[1] + bi.y;
                o.z = xi.z + cp[2] + bi.z;
                o.w = xi.w + cp[3] + bi.w;
                *(float4*)&res[base] = o;
            }
        }
    }
}

// fc1: KP=192, N pad 384 dual; gelu(x1)*x2 -> hid [98304][384] via LDS roundtrip.
__global__ __launch_bounds__(256) void k_fc1(const bf16* __restrict__ A,
                                             const bf16* __restrict__ Bt1,
                                             const float* __restrict__ bb1,
                                             const bf16* __restrict__ Bt2,
                                             const float* __restrict__ bb2,
                                             bf16* __restrict__ hid)
{
    __shared__ __align__(16) bf16 As[128 * 64];
    __shared__ __align__(16) bf16 Bs1[64 * 64];
    __shared__ __align__(16) bf16 Bs2[64 * 64];
    int bid = xswz();                             // 4608 = 768 * 6
    int n0 = (bid % 6) * 64, m0 = (bid / 6) * 128;
    f32x4 a1[2][4] = {}, a2[2][4] = {};
    mm2<192, true>(A, Bt1, Bt2, As, Bs1, Bs2, m0, n0, a1, a2);

    int tid = threadIdx.x, w = tid >> 6, l = tid & 63, q = l >> 4, c = l & 15;
    bf16* Cs = As;
    #pragma unroll
    for (int mt = 0; mt < 2; mt++)
      #pragma unroll
      for (int nt = 0; nt < 4; nt++)
        #pragma unroll
        for (int r = 0; r < 4; r++) {
            int row = w * 32 + mt * 16 + q * 4 + r;
            int colt = nt * 16 + c;
            int col = n0 + colt;
            float hv = 0.f;
            if (col < 360)
                hv = gelu_erf(a1[mt][nt][r] + bb1[col]) * (a2[mt][nt][r] + bb2[col]);
            Cs[cs_idx(row, colt)] = f2b(hv);
        }
    __syncthreads();
    #pragma unroll
    for (int e = 0; e < 4; e++) {
        int gi = e * 256 + tid;
        int row = gi >> 3, j = gi & 7, c8 = j * 8;
        *(uint4*)&hid[(size_t)(m0 + row) * 384 + n0 + c8] =
            *(const uint4*)&Cs[row * 64 + ((j ^ ((row >> 2) & 7)) << 3)];
    }
}

// fc2: KP=384 (hid stride), N pad 192; out += hid@w2 + b (in-place fp32).
// Same fp32-roundtrip + float4 RMW epilogue as proj (rows linear here).
__global__ __launch_bounds__(256) void k_fc2(const bf16* __restrict__ A,
                                             const bf16* __restrict__ Bt,
                                             const float* __restrict__ bias,
                                             float* __restrict__ out)
{
    __shared__ __align__(16) char smem[24576];
    bf16*  As = (bf16*)smem;
    bf16*  Bs = (bf16*)(smem + 16384);
    float* Cs = (float*)smem;                     // [64][76]
    int bid = xswz();                             // 2304
    int n0 = (bid % 3) * 64, m0 = (bid / 3) * 128;
    f32x4 a1[2][4] = {}, a2[2][4];
    mm2<384, false>(A, Bt, nullptr, As, Bs, nullptr, m0, n0, a1, a2);

    int tid = threadIdx.x, w = tid >> 6, l = tid & 63, q = l >> 4, c = l & 15;
    #pragma unroll
    for (int h = 0; h < 2; h++) {
        __syncthreads();
        if ((w >> 1) == h) {
            #pragma unroll
            for (int mt = 0; mt < 2; mt++)
              #pragma unroll
              for (int nt = 0; nt < 4; nt++)
                #pragma unroll
                for (int r = 0; r < 4; r++) {
                    int rl = (w & 1) * 32 + mt * 16 + q * 4 + r;
                    Cs[rl * 76 + nt * 16 + c] = a1[mt][nt][r];
                }
        }
        __syncthreads();
        #pragma unroll
        for (int e = 0; e < 4; e++) {
            int slot = e * 256 + tid;
            int rl = slot >> 4, cq = slot & 15;
            int col = n0 + cq * 4;
            if (col < 180) {
                size_t idx = (size_t)(m0 + h * 64 + rl) * 180 + col;
                float4 ov = *(const float4*)&out[idx];
                float4 bi = *(const float4*)&bias[col];
                const float* cp = &Cs[rl * 76 + cq * 4];
                ov.x += cp[0] + bi.x;
                ov.y += cp[1] + bi.y;
                ov.z += cp[2] + bi.z;
                ov.w += cp[3] + bi.w;
                *(float4*)&out[idx] = ov;
            }
        }
    }
}

// ---------------------------------------------------------------- MFMA attention v2
// Q/K fragments loaded direct from global; mask analytic; bias from transposed
// bf16 table; Vts/Ps XOR-swizzled; LDS 43520B -> 3 blocks/CU.
template<bool MUT>
__global__ __launch_bounds__(256) void k_attn(const bf16* __restrict__ qkv,
                                              const bf16* __restrict__ biasrT,
                                              bf16* __restrict__ aout)
{
    __shared__ __align__(16) bf16 Vts[32 * 136];
    __shared__ __align__(16) bf16 Ps[128 * 136];

    int wh = blockIdx.x, win = wh / 6, nh = wh - win * 6;
    const bf16* qg = qkv + (size_t)wh * 4096;
    const bf16* kg = qg + (size_t)SZPE;
    const bf16* vg = qg + 2 * (size_t)SZPE;
    int tid = threadIdx.x, w = tid >> 6, l = tid & 63, q = l >> 4, c = l & 15;

    // stage V transposed (swizzled): 2 x uint4 global loads per thread
    #pragma unroll
    for (int e = 0; e < 2; e++) {
        int base = (e * 256 + tid) * 8;          // < 4096
        int tok = base >> 5, hd0 = base & 31;
        uint4 vv = *(const uint4*)&vg[base];
        const bf16* pv = (const bf16*)&vv;
        #pragma unroll
        for (int i = 0; i < 8; i++) {
            int hd = hd0 + i;
            Vts[hd * 136 + (tok ^ (((hd >> 3) & 3) << 3))] = pv[i];
        }
    }

    // QK^T direct from global (A/B fragments are contiguous 16B in [128][32] layout)
    f32x4 S[2][8];
    #pragma unroll
    for (int mt = 0; mt < 2; mt++)
        #pragma unroll
        for (int nt = 0; nt < 8; nt++) S[mt][nt] = (f32x4){0.f, 0.f, 0.f, 0.f};
    {
        short8 a[2];
        #pragma unroll
        for (int mt = 0; mt < 2; mt++) {
            int rq = w * 32 + mt * 16 + c;
            if (MUT) rq ^= 64;                   // swap halves for mutual attn
            a[mt] = *(const short8*)&qg[rq * 32 + q * 8];
        }
        #pragma unroll
        for (int nt = 0; nt < 8; nt++) {
            short8 b = *(const short8*)&kg[(nt * 16 + c) * 32 + q * 8];
            #pragma unroll
            for (int mt = 0; mt < 2; mt++) S[mt][nt] = mfma16(a[mt], b, S[mt][nt]);
        }
    }

    // region labels for analytic mask
    int rcnt[2][4], ccnt[8];
    #pragma unroll
    for (int mt = 0; mt < 2; mt++)
        #pragma unroll
        for (int r = 0; r < 4; r++) {
            int row = w * 32 + mt * 16 + q * 4 + r;
            rcnt[mt][r] = wincnt(win, MUT ? (row & 63) : row);
        }
    #pragma unroll
    for (int nt = 0; nt < 8; nt++) {
        int col = nt * 16 + c;
        ccnt[nt] = wincnt(win, MUT ? (col & 63) : col);
    }

    float mx[2][4];
    #pragma unroll
    for (int mt = 0; mt < 2; mt++)
      #pragma unroll
      for (int r = 0; r < 4; r++) mx[mt][r] = -3.0e38f;

    #pragma unroll
    for (int mt = 0; mt < 2; mt++)
      #pragma unroll
      for (int nt = 0; nt < 8; nt++) {
        float bv[4];
        if (!MUT) {
            int col = nt * 16 + c;
            us4 bb = *(const us4*)&biasrT[((size_t)(nh * 128 + col)) * 128
                                          + w * 32 + mt * 16 + q * 4];
            #pragma unroll
            for (int r = 0; r < 4; r++) bv[r] = bu2f(bb[r]);
        }
        bool valid = (w < 2) == (nt < 4);        // wave-uniform (MUT only)
        #pragma unroll
        for (int r = 0; r < 4; r++) {
            float s = S[mt][nt][r];
            if (MUT) {
                s = (rcnt[mt][r] == ccnt[nt]) ? s : s - 100.f;
                s = valid ? s : -30000.f;
            } else {
                s += bv[r];
                if (rcnt[mt][r] != ccnt[nt]) s -= 100.f;
            }
            S[mt][nt][r] = s;
            mx[mt][r] = fmaxf(mx[mt][r], s);
        }
      }
    #pragma unroll
    for (int mt = 0; mt < 2; mt++)
      #pragma unroll
      for (int r = 0; r < 4; r++) {
          float m = mx[mt][r];
          #pragma unroll
          for (int o = 1; o < 16; o <<= 1) m = fmaxf(m, __shfl_xor(m, o, 64));
          mx[mt][r] = m;
      }

    float sm[2][4] = {};
    #pragma unroll
    for (int mt = 0; mt < 2; mt++)
      #pragma unroll
      for (int nt = 0; nt < 8; nt++)
        #pragma unroll
        for (int r = 0; r < 4; r++) {
            float p = __expf(S[mt][nt][r] - mx[mt][r]);
            sm[mt][r] += p;
            Ps[(w * 32 + mt * 16 + q * 4 + r) * 136 + ((nt * 16 + c) ^ (q << 3))] = f2b(p);
        }
    #pragma unroll
    for (int mt = 0; mt < 2; mt++)
      #pragma unroll
      for (int r = 0; r < 4; r++) {
          float s = sm[mt][r];
          #pragma unroll
          for (int o = 1; o < 16; o <<= 1) s += __shfl_xor(s, o, 64);
          sm[mt][r] = s;
      }
    __syncthreads();                              // Vts + Ps ready

    f32x4 O[2][2];
    #pragma unroll
    for (int mt = 0; mt < 2; mt++)
        #pragma unroll
        for (int nt = 0; nt < 2; nt++) O[mt][nt] = (f32x4){0.f, 0.f, 0.f, 0.f};
    #pragma unroll
    for (int ks = 0; ks < 4; ks++) {
        short8 a[2];
        #pragma unroll
        for (int mt = 0; mt < 2; mt++) {
            int row = w * 32 + mt * 16 + c;
            int xr = ((c >> 2) & 3) << 3;         // = (row>>2)&3, matches writer q
            a[mt] = *(const short8*)&Ps[row * 136 + (ks * 32 + ((q << 3) ^ xr))];
        }
        #pragma unroll
        for (int nt = 0; nt < 2; nt++) {
            int hd = nt * 16 + c;
            int xv = ((hd >> 3) & 3) << 3;
            short8 b = *(const short8*)&Vts[hd * 136 + (ks * 32 + ((q << 3) ^ xv))];
            #pragma unroll
            for (int mt = 0; mt < 2; mt++) O[mt][nt] = mfma16(a[mt], b, O[mt][nt]);
        }
    }

    #pragma unroll
    for (int mt = 0; mt < 2; mt++)
      #pragma unroll
      for (int r = 0; r < 4; r++) {
          int row = w * 32 + mt * 16 + q * 4 + r;
          float inv = 1.f / sm[mt][r];
          #pragma unroll
          for (int nt = 0; nt < 2; nt++) {
              int col = nt * 16 + c;
              if (col < 30)
                  aout[((size_t)win * 128 + row) * 384 + (MUT ? 0 : 180) + nh * 30 + col] =
                      f2b(O[mt][nt][r] * inv);
          }
      }
}

// ---------------------------------------------------------------- launch
extern "C" void kernel_launch(void* const* d_in, const int* in_sizes, int n_in,
                              void* d_out, int out_size, void* d_ws, size_t ws_size,
                              hipStream_t stream)
{
    const float* x     = (const float*)d_in[0];
    const float* mask  = (const float*)d_in[1];
    const float* g1    = (const float*)d_in[2];
    const float* b1    = (const float*)d_in[3];
    const float* g2    = (const float*)d_in[4];
    const float* b2    = (const float*)d_in[5];
    const float* wqs   = (const float*)d_in[6];
    const float* bqs   = (const float*)d_in[7];
    const float* wqm   = (const float*)d_in[8];
    const float* bqm   = (const float*)d_in[9];
    const float* rpb   = (const float*)d_in[10];
    const float* posb  = (const float*)d_in[11];
    const float* wproj = (const float*)d_in[12];
    const float* bproj = (const float*)d_in[13];
    const float* w11   = (const float*)d_in[14];
    const float* bf11  = (const float*)d_in[15];
    const float* w12   = (const float*)d_in[16];
    const float* bf12  = (const float*)d_in[17];
    const float* w2    = (const float*)d_in[18];
    const float* bf2   = (const float*)d_in[19];
    const int*   rpi   = (const int*)d_in[20];
    float* out = (float*)d_out;
    (void)mask;   // mask is computed analytically in k_attn

    const size_t need = 265671168;
    if (ws_size < need) { fprintf(stderr, "[tmsa] ws too small: %zu < %zu\n", ws_size, need); return; }

    char* W = (char*)d_ws;
    bf16*  xw     = (bf16*)W;                              // [98304][192]
    bf16*  xwm    = (bf16*)(W + 37748736);                 // [98304][192]
    bf16*  attn   = (bf16*)(W + 75497472);                 // [98304][384]
    bf16*  qkv    = (bf16*)(W + 150994944);                // [3][4608][128][32]
    bf16*  biasrT = (bf16*)(W + 264241152);                // [6][128][128] bf16 (transposed)
    bf16*  Btqs   = (bf16*)(W + 264634368);                // [576][192]
    bf16*  Btqm   = (bf16*)(W + 264855552);                // [576][192]
    float* bbqs   = (float*)(W + 265076736);               // [576]
    float* bbqm   = (float*)(W + 265079040);               // [576]
    bf16*  Btproj = (bf16*)(W + 265081344);                // [192][384]
    bf16*  Btf11  = (bf16*)(W + 265228800);                // [384][192]
    bf16*  Btf12  = (bf16*)(W + 265376256);                // [384][192]
    bf16*  Btf2   = (bf16*)(W + 265523712);                // [192][384]

    k_rpbg<<<dim3(384), 256, 0, stream>>>(rpb, rpi, biasrT);
    k_pack_qkv<<<dim3(432), 256, 0, stream>>>(wqs, bqs, Btqs, bbqs);
    k_pack_qkv<<<dim3(432), 256, 0, stream>>>(wqm, bqm, Btqm, bbqm);
    k_pack<<<dim3(288), 256, 0, stream>>>(wproj, 180, 360, 384, Btproj);
    k_pack<<<dim3(288), 256, 0, stream>>>(w11,   360, 180, 192, Btf11);
    k_pack<<<dim3(288), 256, 0, stream>>>(w12,   360, 180, 192, Btf12);
    k_pack<<<dim3(288), 256, 0, stream>>>(w2,    180, 360, 384, Btf2);

    k_ln<true><<<dim3(24576), 256, 0, stream>>>(x, g1, b1, posb, xw, xwm);
    k_zpad<<<dim3(1152), 256, 0, stream>>>(attn);
    k_qkv<<<dim3(6912), 256, 0, stream>>>(xw, Btqs, bbqs, qkv);
    k_attn<false><<<dim3(4608), 256, 0, stream>>>(qkv, biasrT, attn);
    k_qkv<<<dim3(6912), 256, 0, stream>>>(xwm, Btqm, bbqm, qkv);
    k_attn<true><<<dim3(4608), 256, 0, stream>>>(qkv, biasrT, attn);
    k_proj<<<dim3(2304), 256, 0, stream>>>(attn, Btproj, bproj, x, out);
    k_ln<false><<<dim3(24576), 256, 0, stream>>>(out, g2, b2, nullptr, xw, nullptr);
    k_fc1<<<dim3(4608), 256, 0, stream>>>(xw, Btf11, bf11, Btf12, bf12, attn);
    k_fc2<<<dim3(2304), 256, 0, stream>>>(attn, Btf2, bf2, out);
}